// Round 1
// 399.337 us; speedup vs baseline: 1.2861x; 1.2861x over previous
//
#include <hip/hip_runtime.h>

#define ZN 131072          // B*H*W rows
#define DD 64              // embedding dim
#define KK 1024            // codebook entries
#define BSTRIDE 262144     // 64*64*64 (per-batch stride in z)
#define DSTRIDE 4096       // per-d stride in z (H*W)
#define ZQ_ELEMS 8388608   // 32*64*64*64

// ---- workspace layout ----
// [0,8)                double   loss accumulator
// [8,12)               unsigned flagged-row count
// [16,4112)            float    csq32[1024]    (numpy-emulated fp32)
// [4112,528400)        float    zsq32[131072]  (numpy-emulated fp32)
// [528400,1052688)     int      worklist[131072]
// [1052688,2101264)    u64      pack[131072]   (ordered_dist<<32 | k)
// [2101264,2363408)    float    cbT[64][1024]  (transposed codebook)
// [2363408,2625552)    ushort   cbB[64][2][2][64][8]  bf16 hi/lo B-fragments
//                      layout: ct*2048 + h*1024 + s*512 + lane*8 + j
#define WS_CSQ_OFF   16
#define WS_ZSQ_OFF   4112
#define WS_WORK_OFF  528400
#define WS_PACK_OFF  1052688
#define WS_CBT_OFF   2101264
#define WS_CBB_OFF   2363408

typedef float v2f __attribute__((ext_vector_type(2)));
typedef __attribute__((ext_vector_type(8))) short short8;
typedef __attribute__((ext_vector_type(4))) float f32x4;

// round-to-nearest-even fp32 -> bf16 (data has no NaN/Inf)
__device__ __forceinline__ unsigned short f2bf_rne(float x) {
    unsigned u = __float_as_uint(x);
    return (unsigned short)((u + 0x7fffu + ((u >> 16) & 1u)) >> 16);
}

// numpy-emulated fp32 sum of a[i]^2 over 64 elems (pairwise, 8 accumulators).
__device__ __forceinline__ float np_sumsq64(const float* a) {
    float r0 = __fmul_rn(a[0], a[0]), r1 = __fmul_rn(a[1], a[1]);
    float r2 = __fmul_rn(a[2], a[2]), r3 = __fmul_rn(a[3], a[3]);
    float r4 = __fmul_rn(a[4], a[4]), r5 = __fmul_rn(a[5], a[5]);
    float r6 = __fmul_rn(a[6], a[6]), r7 = __fmul_rn(a[7], a[7]);
#pragma unroll
    for (int i = 8; i < 64; i += 8) {
        r0 = __fadd_rn(r0, __fmul_rn(a[i + 0], a[i + 0]));
        r1 = __fadd_rn(r1, __fmul_rn(a[i + 1], a[i + 1]));
        r2 = __fadd_rn(r2, __fmul_rn(a[i + 2], a[i + 2]));
        r3 = __fadd_rn(r3, __fmul_rn(a[i + 3], a[i + 3]));
        r4 = __fadd_rn(r4, __fmul_rn(a[i + 4], a[i + 4]));
        r5 = __fadd_rn(r5, __fmul_rn(a[i + 5], a[i + 5]));
        r6 = __fadd_rn(r6, __fmul_rn(a[i + 6], a[i + 6]));
        r7 = __fadd_rn(r7, __fmul_rn(a[i + 7], a[i + 7]));
    }
    return __fadd_rn(__fadd_rn(__fadd_rn(r0, r1), __fadd_rn(r2, r3)),
                     __fadd_rn(__fadd_rn(r4, r5), __fadd_rn(r6, r7)));
}

__global__ __launch_bounds__(256) void vq_csq(const float* __restrict__ cb,
                                              float* __restrict__ csq) {
    int k = blockIdx.x * 256 + threadIdx.x;
    csq[k] = np_sumsq64(cb + k * DD);
}

// cbT[d][k] = cb[k][d]   (refine kernel input)
__global__ __launch_bounds__(256) void vq_transpose(const float* __restrict__ cb,
                                                    float* __restrict__ cbT) {
    int i = blockIdx.x * 256 + threadIdx.x;  // i = d*1024 + k
    int d = i >> 10, k = i & 1023;
    cbT[i] = cb[k * DD + d];
}

// Pre-fragment codebook into bf16 hi/lo MFMA B-operand layout.
// B frag for v_mfma_f32_16x16x32_bf16: col = lane&15, k = (lane>>4)*8 + j.
// Step s covers d in [32s,32s+32); frag offset = ct*2048 + h*1024 + s*512 + lane*8 + j.
__global__ __launch_bounds__(256) void vq_prep_b(const float* __restrict__ cb,
                                                 unsigned short* __restrict__ cbB) {
    int i = blockIdx.x * 256 + threadIdx.x;  // i = k*64 + d
    int k = i >> 6, d = i & 63;
    float c = cb[i];
    unsigned short hi = f2bf_rne(c);
    float hf = __uint_as_float((unsigned)hi << 16);
    unsigned short lo = f2bf_rne(c - hf);
    int ct = k >> 4, col = k & 15;
    int s = d >> 5, lg = (d >> 3) & 3, j = d & 7;
    int lane = col + 16 * lg;
    int base = ct * 2048 + s * 512 + lane * 8 + j;
    cbB[base] = hi;          // h = 0
    cbB[base + 1024] = lo;   // h = 1
}

// numpy-emulated fp32 ||z||^2 per row (needed by refine).
__global__ __launch_bounds__(256) void vq_zsq(const float* __restrict__ z,
                                              float* __restrict__ zsq32) {
    int n = blockIdx.x * 256 + threadIdx.x;
    int b = n >> 12, p = n & 4095;
    const float* zp = z + (size_t)b * BSTRIDE + p;
    float r[8];
#pragma unroll
    for (int j = 0; j < 8; ++j) {
        float v = zp[(size_t)j * DSTRIDE];
        r[j] = __fmul_rn(v, v);
    }
#pragma unroll
    for (int i = 8; i < 64; i += 8)
#pragma unroll
        for (int j = 0; j < 8; ++j) {
            float v = zp[(size_t)(i + j) * DSTRIDE];
            r[j] = __fadd_rn(r[j], __fmul_rn(v, v));
        }
    zsq32[n] = __fadd_rn(__fadd_rn(__fadd_rn(r[0], r[1]), __fadd_rn(r[2], r[3])),
                         __fadd_rn(__fadd_rn(r[4], r[5]), __fadd_rn(r[6], r[7])));
}

// -------- MFMA bf16^3 prefilter argmin --------
// block = 64 rows x 4 waves; wave wv scans codes [wv*256, wv*256+256) in 16-code
// tiles. dot = z_hi*c_hi + z_lo*c_hi + z_hi*c_lo via 6 chained 16x16x32 MFMAs
// (worst-case dot err ~4e-6 << the 2e-4 flag threshold, so exactness logic is
// unchanged vs the fp32 prefilter). z tile staged to LDS pre-split into
// A-fragment layout (row = lane&15, k = (lane>>4)*8+j).
__global__ __attribute__((amdgpu_waves_per_eu(2))) __launch_bounds__(256)
void vq_argmin_mfma(const float* __restrict__ z,
                    const unsigned short* __restrict__ cbB,
                    const float* __restrict__ csq,
                    float* __restrict__ idxf_out,
                    unsigned* __restrict__ count,
                    int* __restrict__ worklist) {
    __shared__ __align__(16) unsigned short aFrag[4][2][2][64][8];  // [rt][s][h][lane][j]
    __shared__ float scsq[1024];
    __shared__ float smin1[4][64], smin2[4][64];
    __shared__ int sbest[4][64];

    int t = threadIdx.x;
    int n0 = blockIdx.x * 64;
    int b = n0 >> 12, p0 = n0 & 4095;   // 64 | 4096 -> no batch crossing in block

    for (int i = t; i < 1024; i += 256) scsq[i] = csq[i];

    {   // stage z tile: thread t loads row r = t&63, d-groups g = 2*(t>>6)+{0,1}
        int r = t & 63, gb = t >> 6;
        const float* zp = z + (size_t)b * BSTRIDE + p0 + r;
#pragma unroll
        for (int gg = 0; gg < 2; ++gg) {
            int g = (gb << 1) | gg;  // d in [8g, 8g+8)
            short8 hi8, lo8;
#pragma unroll
            for (int i2 = 0; i2 < 8; ++i2) {
                float v = zp[(size_t)(8 * g + i2) * DSTRIDE];  // coalesced across lanes
                unsigned short h = f2bf_rne(v);
                float hf = __uint_as_float((unsigned)h << 16);
                hi8[i2] = (short)h;
                lo8[i2] = (short)f2bf_rne(v - hf);
            }
            int rt = r >> 4, s = g >> 2, lane = (r & 15) + 16 * (g & 3);
            *(short8*)&aFrag[rt][s][0][lane][0] = hi8;
            *(short8*)&aFrag[rt][s][1][lane][0] = lo8;
        }
    }
    __syncthreads();

    int l = t & 63;
    int wv = __builtin_amdgcn_readfirstlane(t >> 6);

    short8 aH[4][2], aL[4][2];  // [rowtile][k-step]: z_hi, z_lo fragments
#pragma unroll
    for (int rt = 0; rt < 4; ++rt)
#pragma unroll
        for (int s = 0; s < 2; ++s) {
            aH[rt][s] = *(const short8*)&aFrag[rt][s][0][l][0];
            aL[rt][s] = *(const short8*)&aFrag[rt][s][1][l][0];
        }

    // per-lane running min1/min2/best for 16 row-slots (all static-indexed)
    float m1[4][4], m2[4][4];
    int bst[4][4];
#pragma unroll
    for (int rt = 0; rt < 4; ++rt)
#pragma unroll
        for (int r = 0; r < 4; ++r) {
            m1[rt][r] = 3.4e38f;
            m2[rt][r] = 3.4e38f;
            bst[rt][r] = 0;
        }

    int colcode = l & 15;
#pragma unroll 2
    for (int cti = 0; cti < 16; ++cti) {
        int ct = (wv << 4) + cti;
        const unsigned short* bp = cbB + ct * 2048 + (l << 3);
        short8 bh0 = *(const short8*)(bp);           // c_hi, d 0..31
        short8 bh1 = *(const short8*)(bp + 512);     // c_hi, d 32..63
        short8 bl0 = *(const short8*)(bp + 1024);    // c_lo, d 0..31
        short8 bl1 = *(const short8*)(bp + 1536);    // c_lo, d 32..63
        float cs = scsq[(ct << 4) + colcode];
        int code = (ct << 4) + colcode;
#pragma unroll
        for (int rt = 0; rt < 4; ++rt) {
            f32x4 acc = {0.f, 0.f, 0.f, 0.f};
            acc = __builtin_amdgcn_mfma_f32_16x16x32_bf16(aH[rt][0], bh0, acc, 0, 0, 0);
            acc = __builtin_amdgcn_mfma_f32_16x16x32_bf16(aH[rt][1], bh1, acc, 0, 0, 0);
            acc = __builtin_amdgcn_mfma_f32_16x16x32_bf16(aL[rt][0], bh0, acc, 0, 0, 0);
            acc = __builtin_amdgcn_mfma_f32_16x16x32_bf16(aL[rt][1], bh1, acc, 0, 0, 0);
            acc = __builtin_amdgcn_mfma_f32_16x16x32_bf16(aH[rt][0], bl0, acc, 0, 0, 0);
            acc = __builtin_amdgcn_mfma_f32_16x16x32_bf16(aH[rt][1], bl1, acc, 0, 0, 0);
#pragma unroll
            for (int r = 0; r < 4; ++r) {
                float dist = fmaf(-2.f, acc[r], cs);
                bool lt = dist < m1[rt][r];  // strict: ties keep lowest code
                m2[rt][r] = lt ? m1[rt][r] : fminf(m2[rt][r], dist);
                bst[rt][r] = lt ? code : bst[rt][r];
                m1[rt][r] = lt ? dist : m1[rt][r];
            }
        }
    }

    // merge across the 16 lanes (cols) sharing each row: butterfly xor 1,2,4,8
#pragma unroll
    for (int m = 1; m <= 8; m <<= 1) {
#pragma unroll
        for (int rt = 0; rt < 4; ++rt)
#pragma unroll
            for (int r = 0; r < 4; ++r) {
                float o1 = __shfl_xor(m1[rt][r], m, 64);
                float o2 = __shfl_xor(m2[rt][r], m, 64);
                int ob = __shfl_xor(bst[rt][r], m, 64);
                bool take = (o1 < m1[rt][r]) ||
                            (o1 == m1[rt][r] && ob < bst[rt][r]);
                float n2 = take ? fminf(o2, m1[rt][r]) : fminf(m2[rt][r], o1);
                m1[rt][r] = take ? o1 : m1[rt][r];
                bst[rt][r] = take ? ob : bst[rt][r];
                m2[rt][r] = n2;
            }
    }

    // one writer per row-slot into the cross-wave merge arrays
#pragma unroll
    for (int rt = 0; rt < 4; ++rt)
#pragma unroll
        for (int r = 0; r < 4; ++r)
            if ((l & 15) == r) {
                int row = (rt << 4) + ((l >> 4) << 2) + r;
                smin1[wv][row] = m1[rt][r];
                smin2[wv][row] = m2[rt][r];
                sbest[wv][row] = bst[rt][r];
            }
    __syncthreads();

    if (wv == 0) {
        float g1 = smin1[0][l], g2 = smin2[0][l];
        int gb = sbest[0][l];
#pragma unroll
        for (int c = 1; c < 4; ++c) {
            float c1 = smin1[c][l];
            if (c1 < g1) {                 // strict: ties keep lower-k chunk
                g2 = fminf(g1, smin2[c][l]);
                gb = sbest[c][l];
                g1 = c1;
            } else {
                g2 = fminf(g2, c1);
            }
        }
        int n = n0 + l;
        idxf_out[n] = (float)gb;
        // reference fp32 rounding noise can only flip ranking for gaps
        // < ~1.6e-5; prefilter err <~1e-5; flag with big margin -> exact pass.
        if (g2 - g1 < 2e-4f) worklist[atomicAdd(count, 1u)] = n;
    }
}

// -------- reference-fp32-emulated argmin for flagged rows --------
__global__ __launch_bounds__(256) void vq_refine(const float* __restrict__ z,
                                                 const float* __restrict__ cbT,
                                                 const float* __restrict__ csq,
                                                 const float* __restrict__ zsq32,
                                                 const unsigned* __restrict__ count,
                                                 const int* __restrict__ worklist,
                                                 unsigned long long* __restrict__ pack) {
    unsigned cnt = *count;
    unsigned long long total = (unsigned long long)cnt << 10;
    unsigned long long stride = (unsigned long long)gridDim.x * 256;
    for (unsigned long long w = blockIdx.x * 256 + threadIdx.x; w < total; w += stride) {
        unsigned r = (unsigned)(w >> 10);
        unsigned k = (unsigned)(w & 1023);
        int n = worklist[r];
        int b = n >> 12, p = n & 4095;
        const float* zp = z + (size_t)b * BSTRIDE + p;

        double a0 = 0.0, a1 = 0.0, a2 = 0.0, a3 = 0.0;
#pragma unroll
        for (int d = 0; d < DD; d += 4) {
            a0 = fma((double)zp[(size_t)(d + 0) * DSTRIDE], (double)cbT[(d + 0) * KK + k], a0);
            a1 = fma((double)zp[(size_t)(d + 1) * DSTRIDE], (double)cbT[(d + 1) * KK + k], a1);
            a2 = fma((double)zp[(size_t)(d + 2) * DSTRIDE], (double)cbT[(d + 2) * KK + k], a2);
            a3 = fma((double)zp[(size_t)(d + 3) * DSTRIDE], (double)cbT[(d + 3) * KK + k], a3);
        }
        double dot = (a0 + a1) + (a2 + a3);
        float twoC = (float)(2.0 * dot);               // ~sgemm output, correctly rounded
        float dist = __fsub_rn(__fadd_rn(zsq32[n], csq[k]), twoC);  // reference fp32 ops

        unsigned ub = __float_as_uint(dist);
        ub = (ub & 0x80000000u) ? ~ub : (ub | 0x80000000u);  // order-preserving map
        unsigned long long pk = ((unsigned long long)ub << 32) | k;  // ties -> lowest k
#pragma unroll
        for (int off = 32; off; off >>= 1) {
            unsigned long long o = (unsigned long long)__shfl_xor((long long)pk, off, 64);
            pk = pk < o ? pk : o;
        }
        if ((threadIdx.x & 63) == 0) atomicMin(&pack[r], pk);
    }
}

__global__ __launch_bounds__(256) void vq_writeback(const unsigned* __restrict__ count,
                                                    const int* __restrict__ worklist,
                                                    const unsigned long long* __restrict__ pack,
                                                    float* __restrict__ idxf_out) {
    unsigned i = blockIdx.x * 256 + threadIdx.x;
    if (i < *count)
        idxf_out[worklist[i]] = (float)(unsigned)(pack[i] & 0xFFFFFFFFull);
}

// -------- gather z_q + fused loss partial reduction --------
__global__ __launch_bounds__(256) void vq_gather_loss(const float* __restrict__ z,
                                                      const float* __restrict__ cb,
                                                      const float* __restrict__ idxf,
                                                      float* __restrict__ zq_out,
                                                      double* __restrict__ acc) {
    int n = blockIdx.x * 256 + threadIdx.x;
    int b = n >> 12, p = n & 4095;
    const float* zp = z + (size_t)b * BSTRIDE + p;
    float* qp = zq_out + (size_t)b * BSTRIDE + p;
    int k = (int)idxf[n];
    const float* c = cb + k * DD;

    float s = 0.f;
#pragma unroll
    for (int d = 0; d < DD; ++d) {
        float q = c[d];
        float diff = q - zp[(size_t)d * DSTRIDE];
        s = fmaf(diff, diff, s);
        qp[(size_t)d * DSTRIDE] = q;  // z_q_st == z_q numerically
    }

#pragma unroll
    for (int off = 32; off; off >>= 1) s += __shfl_down(s, off, 64);
    __shared__ float partial[4];
    if ((threadIdx.x & 63) == 0) partial[threadIdx.x >> 6] = s;
    __syncthreads();
    if (threadIdx.x == 0) {
        float t = (partial[0] + partial[1]) + (partial[2] + partial[3]);
        atomicAdd(acc, (double)t);
    }
}

__global__ void vq_finalize(const double* __restrict__ acc, float* __restrict__ loss_out) {
    *loss_out = (float)(1.25 * (*acc) / (double)ZQ_ELEMS);
}

extern "C" void kernel_launch(void* const* d_in, const int* in_sizes, int n_in,
                              void* d_out, int out_size, void* d_ws, size_t ws_size,
                              hipStream_t stream) {
    const float* z = (const float*)d_in[0];
    const float* cb = (const float*)d_in[1];
    float* out = (float*)d_out;

    float* zq_out = out;                   // [0, 8388608)
    float* loss_out = out + ZQ_ELEMS;      // [8388608]
    float* idxf_out = out + ZQ_ELEMS + 1;  // [8388609, +131072)

    char* ws = (char*)d_ws;
    double* acc = (double*)ws;
    unsigned* count = (unsigned*)(ws + 8);
    float* csq = (float*)(ws + WS_CSQ_OFF);
    float* zsq32 = (float*)(ws + WS_ZSQ_OFF);
    int* worklist = (int*)(ws + WS_WORK_OFF);
    unsigned long long* pack = (unsigned long long*)(ws + WS_PACK_OFF);
    float* cbT = (float*)(ws + WS_CBT_OFF);
    unsigned short* cbB = (unsigned short*)(ws + WS_CBB_OFF);

    hipMemsetAsync(d_ws, 0, 16, stream);                        // acc=0, count=0
    hipMemsetAsync(ws + WS_PACK_OFF, 0xFF, ZN * 8, stream);     // pack = UINT64_MAX

    vq_csq<<<KK / 256, 256, 0, stream>>>(cb, csq);
    vq_transpose<<<KK * DD / 256, 256, 0, stream>>>(cb, cbT);
    vq_prep_b<<<KK * DD / 256, 256, 0, stream>>>(cb, cbB);
    vq_zsq<<<ZN / 256, 256, 0, stream>>>(z, zsq32);
    vq_argmin_mfma<<<ZN / 64, 256, 0, stream>>>(z, cbB, csq, idxf_out, count, worklist);
    vq_refine<<<2048, 256, 0, stream>>>(z, cbT, csq, zsq32, count, worklist, pack);
    vq_writeback<<<ZN / 256, 256, 0, stream>>>(count, worklist, pack, idxf_out);
    vq_gather_loss<<<ZN / 256, 256, 0, stream>>>(z, cb, idxf_out, zq_out, acc);
    vq_finalize<<<1, 1, 0, stream>>>(acc, loss_out);
}

// Round 2
// 260.238 us; speedup vs baseline: 1.9735x; 1.5345x over previous
//
#include <hip/hip_runtime.h>

#define ZN 131072          // B*H*W rows
#define DD 64              // embedding dim
#define KK 1024            // codebook entries
#define BSTRIDE 262144     // 64*64*64 (per-batch stride in z)
#define DSTRIDE 4096       // per-d stride in z (H*W)
#define ZQ_ELEMS 8388608   // 32*64*64*64

// ---- workspace layout ----
// [0,8)                double   loss accumulator
// [8,12)               unsigned pair count
// [16,4112)            float    csq32[1024]    (numpy-emulated fp32)
// [4112,528400)        float    zsq32[131072]  (numpy-emulated fp32)
// [1052688,2101264)    u64      pack[131072]   (ordered_dist<<32 | k)
// [2363408,2625552)    ushort   cbB[64][2][2][64][8]  bf16 hi/lo B-fragments
// [2625552, +8MB)      u32      pairs[] = (n<<10 | k) candidate list
#define WS_CSQ_OFF   16
#define WS_ZSQ_OFF   4112
#define WS_PACK_OFF  1052688
#define WS_CBB_OFF   2363408
#define WS_PAIR_OFF  2625552
#define PAIR_CAP     2097152u

typedef __attribute__((ext_vector_type(8))) short short8;
typedef __attribute__((ext_vector_type(4))) float f32x4;

// round-to-nearest-even fp32 -> bf16 (data has no NaN/Inf)
__device__ __forceinline__ unsigned short f2bf_rne(float x) {
    unsigned u = __float_as_uint(x);
    return (unsigned short)((u + 0x7fffu + ((u >> 16) & 1u)) >> 16);
}

// numpy-emulated fp32 sum of a[i]^2 over 64 elems (pairwise, 8 accumulators).
__device__ __forceinline__ float np_sumsq64(const float* a) {
    float r0 = __fmul_rn(a[0], a[0]), r1 = __fmul_rn(a[1], a[1]);
    float r2 = __fmul_rn(a[2], a[2]), r3 = __fmul_rn(a[3], a[3]);
    float r4 = __fmul_rn(a[4], a[4]), r5 = __fmul_rn(a[5], a[5]);
    float r6 = __fmul_rn(a[6], a[6]), r7 = __fmul_rn(a[7], a[7]);
#pragma unroll
    for (int i = 8; i < 64; i += 8) {
        r0 = __fadd_rn(r0, __fmul_rn(a[i + 0], a[i + 0]));
        r1 = __fadd_rn(r1, __fmul_rn(a[i + 1], a[i + 1]));
        r2 = __fadd_rn(r2, __fmul_rn(a[i + 2], a[i + 2]));
        r3 = __fadd_rn(r3, __fmul_rn(a[i + 3], a[i + 3]));
        r4 = __fadd_rn(r4, __fmul_rn(a[i + 4], a[i + 4]));
        r5 = __fadd_rn(r5, __fmul_rn(a[i + 5], a[i + 5]));
        r6 = __fadd_rn(r6, __fmul_rn(a[i + 6], a[i + 6]));
        r7 = __fadd_rn(r7, __fmul_rn(a[i + 7], a[i + 7]));
    }
    return __fadd_rn(__fadd_rn(__fadd_rn(r0, r1), __fadd_rn(r2, r3)),
                     __fadd_rn(__fadd_rn(r4, r5), __fadd_rn(r6, r7)));
}

__global__ __launch_bounds__(256) void vq_csq(const float* __restrict__ cb,
                                              float* __restrict__ csq) {
    int k = blockIdx.x * 256 + threadIdx.x;
    csq[k] = np_sumsq64(cb + k * DD);
}

// Pre-fragment codebook into bf16 hi/lo MFMA B-operand layout.
// B frag for v_mfma_f32_16x16x32_bf16: col = lane&15, k = (lane>>4)*8 + j.
__global__ __launch_bounds__(256) void vq_prep_b(const float* __restrict__ cb,
                                                 unsigned short* __restrict__ cbB) {
    int i = blockIdx.x * 256 + threadIdx.x;  // i = k*64 + d
    int k = i >> 6, d = i & 63;
    float c = cb[i];
    unsigned short hi = f2bf_rne(c);
    float hf = __uint_as_float((unsigned)hi << 16);
    unsigned short lo = f2bf_rne(c - hf);
    int ct = k >> 4, col = k & 15;
    int s = d >> 5, lg = (d >> 3) & 3, j = d & 7;
    int lane = col + 16 * lg;
    int base = ct * 2048 + s * 512 + lane * 8 + j;
    cbB[base] = hi;          // h = 0
    cbB[base + 1024] = lo;   // h = 1
}

// numpy-emulated fp32 ||z||^2 per row (needed by pair refine).
__global__ __launch_bounds__(256) void vq_zsq(const float* __restrict__ z,
                                              float* __restrict__ zsq32) {
    int n = blockIdx.x * 256 + threadIdx.x;
    int b = n >> 12, p = n & 4095;
    const float* zp = z + (size_t)b * BSTRIDE + p;
    float r[8];
#pragma unroll
    for (int j = 0; j < 8; ++j) {
        float v = zp[(size_t)j * DSTRIDE];
        r[j] = __fmul_rn(v, v);
    }
#pragma unroll
    for (int i = 8; i < 64; i += 8)
#pragma unroll
        for (int j = 0; j < 8; ++j) {
            float v = zp[(size_t)(i + j) * DSTRIDE];
            r[j] = __fadd_rn(r[j], __fmul_rn(v, v));
        }
    zsq32[n] = __fadd_rn(__fadd_rn(__fadd_rn(r[0], r[1]), __fadd_rn(r[2], r[3])),
                         __fadd_rn(__fadd_rn(r[4], r[5]), __fadd_rn(r[6], r[7])));
}

// -------- MFMA bf16^3 two-phase scan --------
// Phase 1: per-row global min over all 1024 codes (MFMA distances), track best k.
// Phase 2: rescan, emit all (row,k) with dist < gmin+2e-4 into compact pair list.
// Any code that can win under reference fp32 rounding is within ~4e-5 of the
// prefilter min (prefilter err ~4e-6, ref rounding noise ~1.6e-5), so the 2e-4
// emission margin makes the candidate set a strict superset of possible winners.
__global__ __attribute__((amdgpu_waves_per_eu(2))) __launch_bounds__(256)
void vq_scan(const float* __restrict__ z,
             const unsigned short* __restrict__ cbB,
             const float* __restrict__ csq,
             float* __restrict__ idxf_out,
             unsigned* __restrict__ paircnt,
             unsigned* __restrict__ pairs,
             unsigned paircap) {
    __shared__ __align__(16) unsigned short aFrag[4][2][2][64][8];  // [rt][s][h][lane][j]
    __shared__ float scsq[1024];
    __shared__ float smin1[4][64];
    __shared__ int sbest[4][64];
    __shared__ float gmin[64];
    __shared__ int ldsCnt[64];
    __shared__ unsigned candLDS[64][8];

    int t = threadIdx.x;
    int n0 = blockIdx.x * 64;
    int b = n0 >> 12, p0 = n0 & 4095;   // 64 | 4096 -> no batch crossing in block

    for (int i = t; i < 1024; i += 256) scsq[i] = csq[i];
    if (t < 64) ldsCnt[t] = 0;

    {   // stage z tile: thread t loads row r = t&63, d-groups g = 2*(t>>6)+{0,1}
        int r = t & 63, gb = t >> 6;
        const float* zp = z + (size_t)b * BSTRIDE + p0 + r;
#pragma unroll
        for (int gg = 0; gg < 2; ++gg) {
            int g = (gb << 1) | gg;  // d in [8g, 8g+8)
            short8 hi8, lo8;
#pragma unroll
            for (int i2 = 0; i2 < 8; ++i2) {
                float v = zp[(size_t)(8 * g + i2) * DSTRIDE];  // coalesced across lanes
                unsigned short h = f2bf_rne(v);
                float hf = __uint_as_float((unsigned)h << 16);
                hi8[i2] = (short)h;
                lo8[i2] = (short)f2bf_rne(v - hf);
            }
            int rt = r >> 4, s = g >> 2, lane = (r & 15) + 16 * (g & 3);
            *(short8*)&aFrag[rt][s][0][lane][0] = hi8;
            *(short8*)&aFrag[rt][s][1][lane][0] = lo8;
        }
    }
    __syncthreads();

    int l = t & 63;
    int colcode = l & 15;

    short8 aH[4][2], aL[4][2];  // [rowtile][k-step]: z_hi, z_lo fragments
#pragma unroll
    for (int rt = 0; rt < 4; ++rt)
#pragma unroll
        for (int s = 0; s < 2; ++s) {
            aH[rt][s] = *(const short8*)&aFrag[rt][s][0][l][0];
            aL[rt][s] = *(const short8*)&aFrag[rt][s][1][l][0];
        }

    int wv = __builtin_amdgcn_readfirstlane(t >> 6);

    // ---- phase 1: min + best per row-slot ----
    float m1[4][4];
    int bst[4][4];
#pragma unroll
    for (int rt = 0; rt < 4; ++rt)
#pragma unroll
        for (int r = 0; r < 4; ++r) {
            m1[rt][r] = 3.4e38f;
            bst[rt][r] = 0;
        }

#pragma unroll 2
    for (int cti = 0; cti < 16; ++cti) {
        int ct = (wv << 4) + cti;
        const unsigned short* bp = cbB + ct * 2048 + (l << 3);
        short8 bh0 = *(const short8*)(bp);
        short8 bh1 = *(const short8*)(bp + 512);
        short8 bl0 = *(const short8*)(bp + 1024);
        short8 bl1 = *(const short8*)(bp + 1536);
        float cs = scsq[(ct << 4) + colcode];
        int code = (ct << 4) + colcode;
#pragma unroll
        for (int rt = 0; rt < 4; ++rt) {
            f32x4 acc = {0.f, 0.f, 0.f, 0.f};
            acc = __builtin_amdgcn_mfma_f32_16x16x32_bf16(aH[rt][0], bh0, acc, 0, 0, 0);
            acc = __builtin_amdgcn_mfma_f32_16x16x32_bf16(aH[rt][1], bh1, acc, 0, 0, 0);
            acc = __builtin_amdgcn_mfma_f32_16x16x32_bf16(aL[rt][0], bh0, acc, 0, 0, 0);
            acc = __builtin_amdgcn_mfma_f32_16x16x32_bf16(aL[rt][1], bh1, acc, 0, 0, 0);
            acc = __builtin_amdgcn_mfma_f32_16x16x32_bf16(aH[rt][0], bl0, acc, 0, 0, 0);
            acc = __builtin_amdgcn_mfma_f32_16x16x32_bf16(aH[rt][1], bl1, acc, 0, 0, 0);
#pragma unroll
            for (int r = 0; r < 4; ++r) {
                float dist = fmaf(-2.f, acc[r], cs);
                bool lt = dist < m1[rt][r];  // strict: ties keep lowest code
                bst[rt][r] = lt ? code : bst[rt][r];
                m1[rt][r] = lt ? dist : m1[rt][r];
            }
        }
    }

    // merge across the 16 lanes (cols) sharing each row: butterfly xor 1,2,4,8
#pragma unroll
    for (int m = 1; m <= 8; m <<= 1) {
#pragma unroll
        for (int rt = 0; rt < 4; ++rt)
#pragma unroll
            for (int r = 0; r < 4; ++r) {
                float o1 = __shfl_xor(m1[rt][r], m, 64);
                int ob = __shfl_xor(bst[rt][r], m, 64);
                bool take = (o1 < m1[rt][r]) ||
                            (o1 == m1[rt][r] && ob < bst[rt][r]);
                m1[rt][r] = take ? o1 : m1[rt][r];
                bst[rt][r] = take ? ob : bst[rt][r];
            }
    }

    // one writer per row-slot into the cross-wave merge arrays
#pragma unroll
    for (int rt = 0; rt < 4; ++rt)
#pragma unroll
        for (int r = 0; r < 4; ++r)
            if ((l & 15) == r) {
                int row = (rt << 4) + ((l >> 4) << 2) + r;
                smin1[wv][row] = m1[rt][r];
                sbest[wv][row] = bst[rt][r];
            }
    __syncthreads();

    if (t < 64) {
        float g1 = smin1[0][t];
        int gb = sbest[0][t];
#pragma unroll
        for (int c = 1; c < 4; ++c) {
            float c1 = smin1[c][t];
            if (c1 < g1) {  // strict: ties keep lower chunk = lower k
                g1 = c1;
                gb = sbest[c][t];
            }
        }
        gmin[t] = g1;
        idxf_out[n0 + t] = (float)gb;  // prefilter answer; refined rows overwritten later
    }
    __syncthreads();

    // ---- phase 2: rescan (bit-identical dists), emit candidates ----
#pragma unroll 2
    for (int cti = 0; cti < 16; ++cti) {
        int ct = (wv << 4) + cti;
        const unsigned short* bp = cbB + ct * 2048 + (l << 3);
        short8 bh0 = *(const short8*)(bp);
        short8 bh1 = *(const short8*)(bp + 512);
        short8 bl0 = *(const short8*)(bp + 1024);
        short8 bl1 = *(const short8*)(bp + 1536);
        float cs = scsq[(ct << 4) + colcode];
        unsigned code = (unsigned)((ct << 4) + colcode);
#pragma unroll
        for (int rt = 0; rt < 4; ++rt) {
            f32x4 acc = {0.f, 0.f, 0.f, 0.f};
            acc = __builtin_amdgcn_mfma_f32_16x16x32_bf16(aH[rt][0], bh0, acc, 0, 0, 0);
            acc = __builtin_amdgcn_mfma_f32_16x16x32_bf16(aH[rt][1], bh1, acc, 0, 0, 0);
            acc = __builtin_amdgcn_mfma_f32_16x16x32_bf16(aL[rt][0], bh0, acc, 0, 0, 0);
            acc = __builtin_amdgcn_mfma_f32_16x16x32_bf16(aL[rt][1], bh1, acc, 0, 0, 0);
            acc = __builtin_amdgcn_mfma_f32_16x16x32_bf16(aH[rt][0], bl0, acc, 0, 0, 0);
            acc = __builtin_amdgcn_mfma_f32_16x16x32_bf16(aH[rt][1], bl1, acc, 0, 0, 0);
#pragma unroll
            for (int r = 0; r < 4; ++r) {
                float dist = fmaf(-2.f, acc[r], cs);
                int row = (rt << 4) + ((l >> 4) << 2) + r;
                if (dist < gmin[row] + 2e-4f) {
                    int pos = atomicAdd(&ldsCnt[row], 1);
                    if (pos < 8) candLDS[row][pos] = code;
                }
            }
        }
    }
    __syncthreads();

    // ---- emission: block-compacted, 1 global atomic per block ----
    if (t < 64) {
        int c = ldsCnt[t];
        int cc = (c > 8) ? 1024 : c;  // overflow row -> emit all 1024 (ultra-rare)
        int run = cc;
#pragma unroll
        for (int off = 1; off < 64; off <<= 1) {
            int o = __shfl_up(run, off, 64);
            if (t >= off) run += o;
        }
        int total = __shfl(run, 63, 64);
        unsigned base = 0;
        if (t == 63) base = atomicAdd(paircnt, (unsigned)total);
        base = __shfl(base, 63, 64);
        unsigned start = base + (unsigned)(run - cc);
        unsigned nn = (unsigned)(n0 + t) << 10;
        if (c <= 8) {
            for (int i = 0; i < c; ++i)
                if (start + i < paircap) pairs[start + i] = nn | candLDS[t][i];
        } else {
            for (int i = 0; i < 1024; ++i)
                if (start + (unsigned)i < paircap) pairs[start + i] = nn | (unsigned)i;
        }
    }
}

// -------- reference-fp32-emulated distance for candidate pairs --------
// Bit-identical fp64 fma chain to the validated full refine (cbT[d][k]==cb[k][d]).
__global__ __launch_bounds__(256) void vq_refine_pairs(
    const float* __restrict__ z,
    const float* __restrict__ cb,
    const float* __restrict__ csq,
    const float* __restrict__ zsq32,
    const unsigned* __restrict__ paircnt,
    const unsigned* __restrict__ pairs,
    unsigned paircap,
    unsigned long long* __restrict__ pack) {
    unsigned cnt = *paircnt;
    if (cnt > paircap) cnt = paircap;
    unsigned stride = gridDim.x * 256;
    for (unsigned i = blockIdx.x * 256 + threadIdx.x; i < cnt; i += stride) {
        unsigned pr = pairs[i];
        int n = (int)(pr >> 10);
        unsigned k = pr & 1023u;
        int b = n >> 12, p = n & 4095;
        const float* zp = z + (size_t)b * BSTRIDE + p;
        const float* cp = cb + k * DD;

        double a0 = 0.0, a1 = 0.0, a2 = 0.0, a3 = 0.0;
#pragma unroll
        for (int d = 0; d < DD; d += 4) {
            a0 = fma((double)zp[(size_t)(d + 0) * DSTRIDE], (double)cp[d + 0], a0);
            a1 = fma((double)zp[(size_t)(d + 1) * DSTRIDE], (double)cp[d + 1], a1);
            a2 = fma((double)zp[(size_t)(d + 2) * DSTRIDE], (double)cp[d + 2], a2);
            a3 = fma((double)zp[(size_t)(d + 3) * DSTRIDE], (double)cp[d + 3], a3);
        }
        double dot = (a0 + a1) + (a2 + a3);
        float twoC = (float)(2.0 * dot);               // ~sgemm output, correctly rounded
        float dist = __fsub_rn(__fadd_rn(zsq32[n], csq[k]), twoC);  // reference fp32 ops

        unsigned ub = __float_as_uint(dist);
        ub = (ub & 0x80000000u) ? ~ub : (ub | 0x80000000u);  // order-preserving map
        unsigned long long pk = ((unsigned long long)ub << 32) | k;  // ties -> lowest k
        atomicMin(&pack[n], pk);
    }
}

// -------- gather z_q + fused idx writeback + loss partial reduction --------
__global__ __launch_bounds__(256) void vq_gather_loss(const float* __restrict__ z,
                                                      const float* __restrict__ cb,
                                                      const unsigned long long* __restrict__ pack,
                                                      float* __restrict__ idxf,
                                                      float* __restrict__ zq_out,
                                                      double* __restrict__ acc) {
    int n = blockIdx.x * 256 + threadIdx.x;
    int b = n >> 12, p = n & 4095;
    const float* zp = z + (size_t)b * BSTRIDE + p;
    float* qp = zq_out + (size_t)b * BSTRIDE + p;

    unsigned long long pk = pack[n];
    int k;
    if (pk != 0xFFFFFFFFFFFFFFFFull) {
        k = (int)(unsigned)(pk & 0xFFFFFFFFull);
        idxf[n] = (float)k;            // refined answer
    } else {
        k = (int)idxf[n];              // fallback: phase-1 best (pair list overflow)
    }
    const float* c = cb + k * DD;

    float s = 0.f;
#pragma unroll
    for (int d = 0; d < DD; ++d) {
        float q = c[d];
        float diff = q - zp[(size_t)d * DSTRIDE];
        s = fmaf(diff, diff, s);
        qp[(size_t)d * DSTRIDE] = q;  // z_q_st == z_q numerically
    }

#pragma unroll
    for (int off = 32; off; off >>= 1) s += __shfl_down(s, off, 64);
    __shared__ float partial[4];
    if ((threadIdx.x & 63) == 0) partial[threadIdx.x >> 6] = s;
    __syncthreads();
    if (threadIdx.x == 0) {
        float t = (partial[0] + partial[1]) + (partial[2] + partial[3]);
        atomicAdd(acc, (double)t);
    }
}

__global__ void vq_finalize(const double* __restrict__ acc, float* __restrict__ loss_out) {
    *loss_out = (float)(1.25 * (*acc) / (double)ZQ_ELEMS);
}

extern "C" void kernel_launch(void* const* d_in, const int* in_sizes, int n_in,
                              void* d_out, int out_size, void* d_ws, size_t ws_size,
                              hipStream_t stream) {
    const float* z = (const float*)d_in[0];
    const float* cb = (const float*)d_in[1];
    float* out = (float*)d_out;

    float* zq_out = out;                   // [0, 8388608)
    float* loss_out = out + ZQ_ELEMS;      // [8388608]
    float* idxf_out = out + ZQ_ELEMS + 1;  // [8388609, +131072)

    char* ws = (char*)d_ws;
    double* acc = (double*)ws;
    unsigned* paircnt = (unsigned*)(ws + 8);
    float* csq = (float*)(ws + WS_CSQ_OFF);
    float* zsq32 = (float*)(ws + WS_ZSQ_OFF);
    unsigned long long* pack = (unsigned long long*)(ws + WS_PACK_OFF);
    unsigned short* cbB = (unsigned short*)(ws + WS_CBB_OFF);
    unsigned* pairs = (unsigned*)(ws + WS_PAIR_OFF);

    unsigned paircap = 0;
    if (ws_size > WS_PAIR_OFF)
        paircap = (unsigned)((ws_size - WS_PAIR_OFF) / 4);
    if (paircap > PAIR_CAP) paircap = PAIR_CAP;

    hipMemsetAsync(d_ws, 0, 16, stream);                        // acc=0, paircnt=0
    hipMemsetAsync(ws + WS_PACK_OFF, 0xFF, ZN * 8, stream);     // pack = UINT64_MAX

    vq_csq<<<KK / 256, 256, 0, stream>>>(cb, csq);
    vq_prep_b<<<KK * DD / 256, 256, 0, stream>>>(cb, cbB);
    vq_zsq<<<ZN / 256, 256, 0, stream>>>(z, zsq32);
    vq_scan<<<ZN / 64, 256, 0, stream>>>(z, cbB, csq, idxf_out, paircnt, pairs, paircap);
    vq_refine_pairs<<<2048, 256, 0, stream>>>(z, cb, csq, zsq32, paircnt, pairs, paircap, pack);
    vq_gather_loss<<<ZN / 256, 256, 0, stream>>>(z, cb, pack, idxf_out, zq_out, acc);
    vq_finalize<<<1, 1, 0, stream>>>(acc, loss_out);
}